// Round 1
// baseline (244.492 us; speedup 1.0000x reference)
//
#include <hip/hip_runtime.h>
#include <stdint.h>

// ---------------------------------------------------------------------------
// Threefry-2x32, 20 rounds — bit-exact match of JAX's threefry2x32 primitive.
// Host + single-chain device version (pos-mask draws).
// ---------------------------------------------------------------------------
#define TF_ROUND(x0, x1, r)                    \
  {                                            \
    x0 += x1;                                  \
    x1 = (x1 << (r)) | (x1 >> (32 - (r)));     \
    x1 ^= x0;                                  \
  }

__host__ __device__ inline void threefry2x32(uint32_t k0, uint32_t k1,
                                             uint32_t x0, uint32_t x1,
                                             uint32_t& o0, uint32_t& o1) {
  const uint32_t ks2 = k0 ^ k1 ^ 0x1BD11BDAu;
  x0 += k0; x1 += k1;
  TF_ROUND(x0, x1, 13) TF_ROUND(x0, x1, 15) TF_ROUND(x0, x1, 26) TF_ROUND(x0, x1, 6)
  x0 += k1; x1 += ks2 + 1u;
  TF_ROUND(x0, x1, 17) TF_ROUND(x0, x1, 29) TF_ROUND(x0, x1, 16) TF_ROUND(x0, x1, 24)
  x0 += ks2; x1 += k0 + 2u;
  TF_ROUND(x0, x1, 13) TF_ROUND(x0, x1, 15) TF_ROUND(x0, x1, 26) TF_ROUND(x0, x1, 6)
  x0 += k0; x1 += k1 + 3u;
  TF_ROUND(x0, x1, 17) TF_ROUND(x0, x1, 29) TF_ROUND(x0, x1, 16) TF_ROUND(x0, x1, 24)
  x0 += k1; x1 += ks2 + 4u;
  TF_ROUND(x0, x1, 13) TF_ROUND(x0, x1, 15) TF_ROUND(x0, x1, 26) TF_ROUND(x0, x1, 6)
  x0 += ks2; x1 += k0 + 5u;
  o0 = x0; o1 = x1;
}

// ---------------------------------------------------------------------------
// 4-wide lockstep threefry (partitionable mode, x0-counter = 0):
// forced v_alignbit rotates + explicit ILP-4 so the dependent chain per wave
// is 4x shallower than the old serialized version (VGPR_Count was 12 -> the
// compiler had fused the 8 chains into ONE 73-deep dependent chain).
// ---------------------------------------------------------------------------
#define RND4(r)                                                     \
  _Pragma("unroll") for (int e = 0; e < 4; ++e) {                   \
    x0[e] += x1[e];                                                 \
    x1[e] = __builtin_amdgcn_alignbit(x1[e], x1[e], 32u - (r));     \
    x1[e] ^= x0[e];                                                 \
  }
#define INJ4(a, b)                                                  \
  _Pragma("unroll") for (int e = 0; e < 4; ++e) {                   \
    x0[e] += (a);                                                   \
    x1[e] += (b);                                                   \
  }

// tbk = counter_base + k1 (per-thread, precomputed); lit = compile-time chunk
// offset so x1-init is a single literal add per element.
__device__ __forceinline__ void tf4(uint32_t k0, uint32_t k1, uint32_t ks2,
                                    uint32_t tbk, uint32_t lit, uint32_t out[4]) {
  uint32_t x0[4], x1[4];
#pragma unroll
  for (int e = 0; e < 4; ++e) { x0[e] = k0; x1[e] = tbk + (lit + (uint32_t)e); }
  RND4(13) RND4(15) RND4(26) RND4(6)
  INJ4(k1, ks2 + 1u)
  RND4(17) RND4(29) RND4(16) RND4(24)
  INJ4(ks2, k0 + 2u)
  RND4(13) RND4(15) RND4(26) RND4(6)
  INJ4(k0, k1 + 3u)
  RND4(17) RND4(29) RND4(16) RND4(24)
  INJ4(k1, ks2 + 4u)
  RND4(13) RND4(15) RND4(26) RND4(6)
#pragma unroll
  for (int e = 0; e < 4; ++e) out[e] = (x0[e] + ks2) ^ (x1[e] + (k0 + 5u));
}

// ---------------------------------------------------------------------------
// Problem constants (shapes fixed by the reference).
// ---------------------------------------------------------------------------
constexpr int B = 16;
constexpr int N = 1024;
constexpr int G = 2000;
constexpr int NUM_ROWS = B * N;                      // 16384
constexpr uint32_t RANK = (uint32_t)(G - 800 - 1);   // 1199
constexpr long long EXPR_ELEMS = (long long)NUM_ROWS * G;  // 32,768,000
constexpr int ROWS_PER_BLOCK = 4;                    // one wave per row

typedef int v4i __attribute__((ext_vector_type(4)));

// ---------------------------------------------------------------------------
// One WAVE per (b,n) row; 4 rows per 256-thread block; ZERO __syncthreads.
// Each wave owns a private 256-bin LDS histogram + candidate buffer, so all
// ordering is same-wave LDS ordering (per-wave FIFO on the DS pipe) — waves
// never convoy at block barriers and no wave idles during another's scan.
//   gen     : 8 chunks x 4 elems/lane (lane*4 contiguous -> dwordx4 stores);
//             chunk 7 is partial (lanes 0..51); lanes 52..56 do pos draws.
//   scan    : per-wave shfl butterfly over its own 256 bins, winner via ballot.
//   collect : rare-divergent ds_add_rtn into per-wave cand[].
//   rank    : shfl-based exact kthvalue among ~8 candidates.
//   store   : nontemporal dwordx4, 1KB contiguous per wave-instruction.
// ---------------------------------------------------------------------------
__global__ __launch_bounds__(256) void fused_mask_kernel(
    int32_t* __restrict__ out_expr, int32_t* __restrict__ out_pos,
    uint32_t ke0, uint32_t ke1,
    uint32_t kr0, uint32_t kr1,
    uint32_t ah0, uint32_t ah1, uint32_t al0, uint32_t al1,
    uint32_t bh0, uint32_t bh1, uint32_t bl0, uint32_t bl1) {
  __shared__ alignas(16) uint32_t hist[ROWS_PER_BLOCK][256];
  __shared__ uint32_t cand[ROWS_PER_BLOCK][64];
  __shared__ uint32_t cnt[ROWS_PER_BLOCK];

  const int t = threadIdx.x;
  const int lane = t & 63;
  const int w = t >> 6;
  const uint32_t row = blockIdx.x * (uint32_t)ROWS_PER_BLOCK + (uint32_t)w;
  const uint32_t rbase = row * (uint32_t)G;

  // Zero this wave's histogram (one ds_write_b128/lane) + counter.
  {
    uint4 z = make_uint4(0u, 0u, 0u, 0u);
    *reinterpret_cast<uint4*>(&hist[w][lane * 4]) = z;
  }
  if (lane == 0) cnt[w] = 0u;
  __builtin_amdgcn_wave_barrier();  // scheduling fence only (no code)

  const uint32_t ks2 = ke0 ^ ke1 ^ 0x1BD11BDAu;
  const uint32_t tbk = rbase + (uint32_t)(lane << 2) + ke1;

  uint32_t m[32];
  uint32_t pb = 0u;

  // --- Generation: 7 full chunks of 4 contiguous elements per lane.
#pragma unroll
  for (int j = 0; j < 7; ++j) {
    uint32_t o[4];
    tf4(ke0, ke1, ks2, tbk, (uint32_t)(j * 256), o);
#pragma unroll
    for (int e = 0; e < 4; ++e) {
      m[j * 4 + e] = o[e] >> 9;              // 23-bit mantissa int, monotone
      atomicAdd(&hist[w][o[e] >> 24], 1u);   // top-8-bit bucket (== m>>15)
    }
  }
  // --- Partial chunk 7: lanes 0..51 cover elements 1792..1999; lanes 52..56
  // --- compute the 5 pos-mask threefry draws for this row in the shadow.
  if (lane < 52) {
    uint32_t o[4];
    tf4(ke0, ke1, ks2, tbk, 1792u, o);
#pragma unroll
    for (int e = 0; e < 4; ++e) {
      m[28 + e] = o[e] >> 9;
      atomicAdd(&hist[w][o[e] >> 24], 1u);
    }
  } else {
#pragma unroll
    for (int e = 0; e < 4; ++e) m[28 + e] = 0xFFFFFFFFu;  // sentinel: never matches bucket
    if (lane < 57) {
      uint32_t pk0, pk1;
      switch (lane) {
        case 52: pk0 = kr0; pk1 = kr1; break;
        case 53: pk0 = ah0; pk1 = ah1; break;
        case 54: pk0 = al0; pk1 = al1; break;
        case 55: pk0 = bh0; pk1 = bh1; break;
        default: pk0 = bl0; pk1 = bl1; break;
      }
      uint32_t y0, y1;
      threefry2x32(pk0, pk1, 0u, row, y0, y1);
      pb = y0 ^ y1;
    }
  }
  __builtin_amdgcn_wave_barrier();

  // --- Per-wave scan of its own 256 bins (same-wave DS ordering guarantees
  // --- the atomics above are visible). Winner broadcast via ballot+shfl.
  uint4 h = *reinterpret_cast<const uint4*>(&hist[w][lane * 4]);
  uint32_t tot = h.x + h.y + h.z + h.w;
  uint32_t x = tot;
#pragma unroll
  for (int d = 1; d < 64; d <<= 1) {
    uint32_t o = __shfl_up(x, d, 64);
    if (lane >= d) x += o;
  }
  const uint32_t e0 = x - tot;  // exclusive prefix of bucket 4*lane
  bool found = (e0 <= RANK) && (RANK < x);
  uint32_t bl_ = 0u, kl = 0u;
  if (found) {
    uint32_t e1 = e0 + h.x, e2 = e1 + h.y, e3 = e2 + h.z;
    if (RANK < e1)      { bl_ = 4u * lane + 0u; kl = RANK - e0; }
    else if (RANK < e2) { bl_ = 4u * lane + 1u; kl = RANK - e1; }
    else if (RANK < e3) { bl_ = 4u * lane + 2u; kl = RANK - e2; }
    else                { bl_ = 4u * lane + 3u; kl = RANK - e3; }
  }
  unsigned long long bm = __ballot(found);
  const int src = __builtin_ctzll(bm);
  const uint32_t bucket = (uint32_t)__shfl((int)bl_, src, 64);
  const uint32_t kk = (uint32_t)__shfl((int)kl, src, 64);

  // --- Collect the target bucket's candidates (~7.8 expected; 64 cap is
  // --- ~1e-35 overflow probability at Poisson(7.8)).
#pragma unroll
  for (int i = 0; i < 32; ++i) {
    if ((m[i] >> 15) == bucket) {
      uint32_t p = atomicAdd(&cnt[w], 1u);
      if (p < 64u) cand[w][p] = m[i];
    }
  }
  __builtin_amdgcn_wave_barrier();

  // --- Exact rank among candidates, shfl-based (value at global sorted
  // --- position RANK is tie-break invariant).
  uint32_t c = cnt[w];
  c = (uint32_t)__builtin_amdgcn_readfirstlane((int)c);
  if (c > 64u) c = 64u;
  uint32_t myc = cand[w][lane];
  uint32_t r = 0u;
  for (uint32_t j = 0; j < c; ++j) {
    uint32_t vj = (uint32_t)__shfl((int)myc, (int)j, 64);
    r += (vj < myc || (vj == myc && j < (uint32_t)lane)) ? 1u : 0u;
  }
  bool win = ((uint32_t)lane < c) && (r == kk);
  unsigned long long wm = __ballot(win);
  const uint32_t thr = (uint32_t)__shfl((int)myc, __builtin_ctzll(wm), 64);

  // --- Pos-mask combine (bit-exact logic; lanes 0..2 store dims 0..2).
  {
    uint32_t p0 = (uint32_t)__shfl((int)pb, 52, 64);
    uint32_t p1 = (uint32_t)__shfl((int)pb, 53, 64);
    uint32_t p2 = (uint32_t)__shfl((int)pb, 54, 64);
    uint32_t p3 = (uint32_t)__shfl((int)pb, 55, 64);
    uint32_t p4 = (uint32_t)__shfl((int)pb, 56, 64);
    if (lane < 3) {
      union { uint32_t u; float f; } cvt;
      cvt.u = (p0 >> 9) | 0x3F800000u;
      float rr = cvt.f - 1.0f;
      const float THR2 = (float)(0.33 * 0.3);
      const float THR1 = (float)0.33;
      bool two = rr < THR2;
      bool one = (rr < THR1) && !two;
      int dim1 = (int)(((p1 % 3u) + (p2 % 3u)) % 3u);
      int excl = (int)(((p3 % 3u) + (p4 % 3u)) % 3u);
      bool mval = two ? (lane != excl) : (one ? (lane == dim1) : false);
      out_pos[row * 3u + (uint32_t)lane] = mval ? 1 : 0;
    }
  }

  // --- Streaming stores: 131 MB, no reuse.
  int32_t* op = out_expr + rbase + (uint32_t)(lane << 2);
#pragma unroll
  for (int j = 0; j < 7; ++j) {
    v4i a;
    a.x = (m[j * 4 + 0] >= thr) ? 1 : 0;
    a.y = (m[j * 4 + 1] >= thr) ? 1 : 0;
    a.z = (m[j * 4 + 2] >= thr) ? 1 : 0;
    a.w = (m[j * 4 + 3] >= thr) ? 1 : 0;
    __builtin_nontemporal_store(a, (v4i*)(op + j * 256));
  }
  if (lane < 52) {
    v4i a;
    a.x = (m[28] >= thr) ? 1 : 0;
    a.y = (m[29] >= thr) ? 1 : 0;
    a.z = (m[30] >= thr) ? 1 : 0;
    a.w = (m[31] >= thr) ? 1 : 0;
    __builtin_nontemporal_store(a, (v4i*)(op + 1792));
  }
}

// ---------------------------------------------------------------------------
// Launch
// ---------------------------------------------------------------------------
extern "C" void kernel_launch(void* const* d_in, const int* in_sizes, int n_in,
                              void* d_out, int out_size, void* d_ws, size_t ws_size,
                              hipStream_t stream) {
  (void)d_in; (void)in_sizes; (void)n_in; (void)d_ws; (void)ws_size; (void)out_size;

  // Host-side key derivation (partitionable fold-like split — verified):
  //   base = key(42) = (0, 42)
  //   ke, kp   = split(base)    -> TF(base,(0,0)), TF(base,(0,1))
  //   kr,k1,k2 = split(kp, 3)   -> TF(kp,(0,j)), j=0..2
  //   randint internal: split(k1) -> ah,al ; split(k2) -> bh,bl
  uint32_t ke0, ke1, kp0, kp1;
  threefry2x32(0u, 42u, 0u, 0u, ke0, ke1);
  threefry2x32(0u, 42u, 0u, 1u, kp0, kp1);
  uint32_t kr0, kr1, ka0, ka1, kb0, kb1;
  threefry2x32(kp0, kp1, 0u, 0u, kr0, kr1);
  threefry2x32(kp0, kp1, 0u, 1u, ka0, ka1);
  threefry2x32(kp0, kp1, 0u, 2u, kb0, kb1);
  uint32_t ah0, ah1, al0, al1, bh0, bh1, bl0, bl1;
  threefry2x32(ka0, ka1, 0u, 0u, ah0, ah1);
  threefry2x32(ka0, ka1, 0u, 1u, al0, al1);
  threefry2x32(kb0, kb1, 0u, 0u, bh0, bh1);
  threefry2x32(kb0, kb1, 0u, 1u, bl0, bl1);

  int32_t* out_expr = (int32_t*)d_out;
  int32_t* out_pos = out_expr + EXPR_ELEMS;

  fused_mask_kernel<<<NUM_ROWS / ROWS_PER_BLOCK, 256, 0, stream>>>(
      out_expr, out_pos, ke0, ke1, kr0, kr1,
      ah0, ah1, al0, al1, bh0, bh1, bl0, bl1);
}